// Round 3
// baseline (5367.799 us; speedup 1.0000x reference)
//
#include <hip/hip_runtime.h>
#include <math.h>

#define Bb 256
#define Tt 256
#define Ff 128
#define Hh 512
#define KTOT 768   // 2F+H
#define NC 2048    // 4*H  (gate cols: colH*4 + {r,z,i_n,h_n})

typedef unsigned short u16;
typedef unsigned int   u32;
typedef __attribute__((ext_vector_type(8))) short s8v;   // 8 bf16 (4 VGPRs)
typedef __attribute__((ext_vector_type(4))) float f4v;   // 4 fp32 acc

// ---------------- ws layout (bytes) ----------------
// gamma  : u16 [Tt*Bb*Hh]   = 67,108,864   [T,B,H]
// xrep   : u16 [Bb*Tt*Ff]   = 16,777,216
// mbf    : u16 [Bb*Tt*Ff]   = 16,777,216
// wfrag  : u16 [NC*KTOT]    =  3,145,728   frag-major (k_wcomb)
// whfrag : u16 [8*4*8*64*8] =    262,144   frag-major Wh hi|lo (k_wh)
// biasc  : f32 [NC]         =      8,192
// hbuf   : f32 [2*Bb*Hh]    =  1,048,576   ping-pong
// bar    : u32 [256]        =      1,024   16 row-group flag lines
// total ≈ 105.1 MB (< 141.6 MB proven in round 1)
#define OFF_GAMMA  0ull
#define OFF_XREP   (OFF_GAMMA  + 67108864ull)
#define OFF_MBF    (OFF_XREP   + 16777216ull)
#define OFF_WFRAG  (OFF_MBF    + 16777216ull)
#define OFF_WHFRAG (OFF_WFRAG  + 3145728ull)
#define OFF_BIASC  (OFF_WHFRAG + 262144ull)
#define OFF_HBUF   (OFF_BIASC  + 8192ull)
#define OFF_BAR    (OFF_HBUF   + 1048576ull)

__device__ __forceinline__ u16 f2b(float x) {   // fp32 -> bf16 RNE
    u32 u = __float_as_uint(x);
    return (u16)((u + 0x7FFFu + ((u >> 16) & 1u)) >> 16);
}
__device__ __forceinline__ float b2f(u16 b) {
    return __uint_as_float(((u32)b) << 16);
}

__global__ __launch_bounds__(256) void k_zero_bar(u32* p) {
    p[threadIdx.x] = 0u;
}

__device__ __forceinline__ float xrep_one(float x, float m, float d, float l,
                                          float w, float bb, float em) {
    float gx = expf(-fmaxf(d * w + bb, 0.f));
    float xh = gx * l + (1.f - gx) * em;
    return m * x + (1.f - m) * xh;
}

// Elementwise precompute: x_rep and m in bf16, layout [B][T][F].
__global__ __launch_bounds__(256) void k_prep(const float* __restrict__ values,
                                              const float* __restrict__ masks,
                                              const float* __restrict__ deltas,
                                              const float* __restrict__ locf,
                                              const float* __restrict__ emean,
                                              const float* __restrict__ wx,
                                              const float* __restrict__ bxp,
                                              u16* __restrict__ xrep,
                                              u16* __restrict__ mbf) {
    int idx = blockIdx.x * 256 + threadIdx.x;   // < B*T*F/4
    int e = idx * 4;
    int f = e & 127;
    float4 xv = *(const float4*)&values[e];
    float4 mv = *(const float4*)&masks[e];
    float4 dv = *(const float4*)&deltas[e];
    float4 lv = *(const float4*)&locf[e];
    float4 wv = *(const float4*)&wx[f];
    float4 bv = *(const float4*)&bxp[f];
    float4 ev = *(const float4*)&emean[f];
    u16 o[4], mo[4];
    o[0] = f2b(xrep_one(xv.x, mv.x, dv.x, lv.x, wv.x, bv.x, ev.x));
    o[1] = f2b(xrep_one(xv.y, mv.y, dv.y, lv.y, wv.y, bv.y, ev.y));
    o[2] = f2b(xrep_one(xv.z, mv.z, dv.z, lv.z, wv.z, bv.z, ev.z));
    o[3] = f2b(xrep_one(xv.w, mv.w, dv.w, lv.w, wv.w, bv.w, ev.w));
    mo[0] = f2b(mv.x); mo[1] = f2b(mv.y); mo[2] = f2b(mv.z); mo[3] = f2b(mv.w);
    *(uint2*)&xrep[e] = *(uint2*)o;
    *(uint2*)&mbf[e]  = *(uint2*)mo;
}

// Combined GRU weight, frag-major bf16 (same proven layout as round 2).
__global__ __launch_bounds__(256) void k_wcomb(const float* __restrict__ W_ih,
                                               const float* __restrict__ W_hh,
                                               const float* __restrict__ b_ih,
                                               const float* __restrict__ b_hh,
                                               u16* __restrict__ wfrag,
                                               float* __restrict__ biasc) {
    int G = blockIdx.x * 256 + threadIdx.x;   // < NC*KTOT/8 = 196608
    int lane = G & 63;
    int q = G >> 6;
    int ki = q % 24; q /= 24;
    int nt = q & 1;  q >>= 1;
    int wv = q & 3;  q >>= 2;
    int bx = q;                                // 0..15
    int c = bx * 128 + wv * 32 + nt * 16 + (lane & 15);
    int kbase = ki * 32 + (lane >> 4) * 8;
    int g = c & 3, jH = c >> 2;
    u16 o[8];
#pragma unroll
    for (int j = 0; j < 8; ++j) {
        int k = kbase + j;
        float w;
        if (g < 3) {
            w = W_ih[(size_t)(g * Hh + jH) * KTOT + k];
            if (g < 2 && k >= Ff && k < Ff + Hh) w += W_hh[(size_t)(g * Hh + jH) * Hh + (k - Ff)];
        } else {
            w = (k >= Ff && k < Ff + Hh) ? W_hh[(size_t)(2 * Hh + jH) * Hh + (k - Ff)] : 0.f;
        }
        o[j] = f2b(w);
    }
    *(uint4*)&wfrag[(size_t)G * 8] = *(uint4*)o;
    if (ki == 0 && (lane >> 4) == 0) {
        float bv;
        if (g == 0)      bv = b_ih[jH] + b_hh[jH];
        else if (g == 1) bv = b_ih[Hh + jH] + b_hh[Hh + jH];
        else if (g == 2) bv = b_ih[2 * Hh + jH];
        else             bv = b_hh[2 * Hh + jH];
        biasc[c] = bv;
    }
}

// Wh in B-frag-major bf16, K duplicated (hi|lo rows see same Wh):
// index = (((ct*4 + nt)*8 + ki)*64 + ls), col = ct*64+nt*16+(ls&15), k = ki*32+(ls>>4)*8+j.
__global__ __launch_bounds__(256) void k_wh(const float* __restrict__ Wh,
                                            u16* __restrict__ whfrag) {
    int G = blockIdx.x * 256 + threadIdx.x;   // < 16384
    int ls = G & 63;
    int q = G >> 6;
    int ki = q & 7; q >>= 3;
    int nt = q & 3; q >>= 2;
    int ct = q;                               // 0..7
    int col = ct * 64 + nt * 16 + (ls & 15);
    int kbase = ki * 32 + (ls >> 4) * 8;
    u16 o[8];
#pragma unroll
    for (int j = 0; j < 8; ++j) {
        int kk = kbase + j;
        int f = (kk < 128) ? kk : kk - 128;
        o[j] = f2b(Wh[col * Ff + f]);
    }
    *(uint4*)&whfrag[(size_t)G * 8] = *(uint4*)o;
}

// gamma via MFMA with deltas split d = d_hi + d_lo (two bf16), K=256.
// grid (TB/64, H/64) = (1024, 8). Wave w owns 16 rows x 64 cols.
__global__ __launch_bounds__(256) void k_gamma2(const float* __restrict__ deltas,
                                                const u16* __restrict__ whfrag,
                                                const float* __restrict__ bh,
                                                u16* __restrict__ gamma) {
    __shared__ u16 A_s[4 * 8 * 64 * 8];   // 32 KB
    __shared__ u16 B_s[4 * 8 * 64 * 8];   // 32 KB
    int tid = threadIdx.x;
    int lane = tid & 63, w = tid >> 6;
    int bt0 = blockIdx.x * 64;
    int c0  = blockIdx.y * 64;

    const uint4* wf4 = (const uint4*)whfrag;
#pragma unroll
    for (int s = 0; s < 8; ++s) {
        int G = tid + s * 256;
        *(uint4*)&B_s[G * 8] = wf4[blockIdx.y * 2048 + G];
    }
#pragma unroll
    for (int s = 0; s < 8; ++s) {
        int G = tid + s * 256;
        int rt = G >> 9, ki = (G >> 6) & 7, ls = G & 63;
        int row = rt * 16 + (ls & 15);
        int kbase = ki * 32 + (ls >> 4) * 8;
        int bt = bt0 + row;
        int b = bt & 255, tt = bt >> 8;
        int f = (kbase < 128) ? kbase : (kbase - 128);
        const float* dp = &deltas[b * (Tt * Ff) + tt * Ff + f];
        float4 d0 = *(const float4*)dp;
        float4 d1 = *(const float4*)(dp + 4);
        float dv[8] = {d0.x, d0.y, d0.z, d0.w, d1.x, d1.y, d1.z, d1.w};
        u16 o[8];
        if (kbase < 128) {
#pragma unroll
            for (int j = 0; j < 8; ++j) o[j] = f2b(dv[j]);
        } else {
#pragma unroll
            for (int j = 0; j < 8; ++j) {
                u16 h = f2b(dv[j]);
                o[j] = f2b(dv[j] - b2f(h));
            }
        }
        *(uint4*)&A_s[G * 8] = *(uint4*)o;
    }
    __syncthreads();

    f4v acc[4];
#pragma unroll
    for (int nt = 0; nt < 4; ++nt) acc[nt] = (f4v){0.f, 0.f, 0.f, 0.f};
#pragma unroll
    for (int ki = 0; ki < 8; ++ki) {
        s8v a = *(const s8v*)&A_s[((w * 8 + ki) * 64 + lane) * 8];
#pragma unroll
        for (int nt = 0; nt < 4; ++nt) {
            s8v b = *(const s8v*)&B_s[((nt * 8 + ki) * 64 + lane) * 8];
            acc[nt] = __builtin_amdgcn_mfma_f32_16x16x32_bf16(a, b, acc[nt], 0, 0, 0);
        }
    }
    int rq = (lane >> 4) * 4;
#pragma unroll
    for (int nt = 0; nt < 4; ++nt) {
        int col = c0 + nt * 16 + (lane & 15);
        float bhv = bh[col];
#pragma unroll
        for (int r = 0; r < 4; ++r) {
            int bt = bt0 + w * 16 + rq + r;
            gamma[(size_t)bt * Hh + col] = f2b(expf(-fmaxf(acc[nt][r] + bhv, 0.f)));
        }
    }
}

// Persistent scan: one launch, 256 blocks (1/CU), weights in VGPRs for all 256 steps.
// Row-group barrier: 16 flags in one 64B line per `by`; release/acquire __threadfence.
__global__ __launch_bounds__(256, 1) void k_scan(const u16* __restrict__ xrep,
                                                 const u16* __restrict__ mbf,
                                                 const u16* __restrict__ gamma,
                                                 const u16* __restrict__ wfrag,
                                                 const float* __restrict__ biasc,
                                                 float* __restrict__ hbuf,
                                                 u32* __restrict__ bar,
                                                 float* __restrict__ hs,
                                                 float* __restrict__ hlast) {
    __shared__ u16  A_s[24 * 64 * 8];   // 24.6 KB
    __shared__ float E_s[16][132];      // 8.45 KB

    int tid = threadIdx.x;
    int lane = tid & 63, w = tid >> 6;
    int bid = blockIdx.x;
    int bx = bid & 15, by = bid >> 4;
    int r0 = by * 16;

    // ---- preload B fragments (stay in VGPRs for all steps) ----
    uint4 Bf[48];
    const uint4* wf4 = (const uint4*)wfrag;
#pragma unroll
    for (int nt = 0; nt < 2; ++nt)
#pragma unroll
        for (int ki = 0; ki < 24; ++ki)
            Bf[nt * 24 + ki] = wf4[(size_t)((((bx * 4 + w) * 2 + nt) * 24 + ki) * 64 + lane)];

    for (int t = 0; t < Tt; ++t) {
        const float* hprev = hbuf + (t & 1) * (Bb * Hh);
        float* hnext = hbuf + ((t + 1) & 1) * (Bb * Hh);

        // ---- stage A tile (16 rows x 768 K bf16), frag-major ----
#pragma unroll
        for (int s = 0; s < 6; ++s) {
            int G = tid + s * 256;            // < 1536
            int ki = G >> 6;                  // wave-uniform
            int ls = G & 63;
            int row = ls & 15;
            int kbase = ki * 32 + (ls >> 4) * 8;
            int b = r0 + row;
            uint4 out;
            if (kbase < 128) {
                out = *(const uint4*)&xrep[(size_t)b * (Tt * Ff) + t * Ff + kbase];
            } else if (kbase < 640) {
                if (t == 0) {
                    out.x = out.y = out.z = out.w = 0u;
                } else {
                    int kh = kbase - 128;
                    const float* hp = &hprev[b * Hh + kh];
                    float4 h0 = *(const float4*)hp;
                    float4 h1 = *(const float4*)(hp + 4);
                    u16 g[8];
                    *(uint4*)g = *(const uint4*)&gamma[((size_t)t * Bb + b) * Hh + kh];
                    u16 o[8];
                    o[0] = f2b(h0.x * b2f(g[0])); o[1] = f2b(h0.y * b2f(g[1]));
                    o[2] = f2b(h0.z * b2f(g[2])); o[3] = f2b(h0.w * b2f(g[3]));
                    o[4] = f2b(h1.x * b2f(g[4])); o[5] = f2b(h1.y * b2f(g[5]));
                    o[6] = f2b(h1.z * b2f(g[6])); o[7] = f2b(h1.w * b2f(g[7]));
                    out = *(uint4*)o;
                }
            } else {
                out = *(const uint4*)&mbf[(size_t)b * (Tt * Ff) + t * Ff + (kbase - 640)];
            }
            *(uint4*)&A_s[G * 8] = out;
        }
        __syncthreads();

        // ---- MFMA: 24 k-iters x 2 N-tiles ----
        f4v acc0 = {0.f, 0.f, 0.f, 0.f};
        f4v acc1 = {0.f, 0.f, 0.f, 0.f};
#pragma unroll
        for (int ki = 0; ki < 24; ++ki) {
            s8v a = *(const s8v*)&A_s[(ki * 64 + lane) * 8];
            acc0 = __builtin_amdgcn_mfma_f32_16x16x32_bf16(a, __builtin_bit_cast(s8v, Bf[ki]), acc0, 0, 0, 0);
            acc1 = __builtin_amdgcn_mfma_f32_16x16x32_bf16(a, __builtin_bit_cast(s8v, Bf[24 + ki]), acc1, 0, 0, 0);
        }

        // ---- C layout -> LDS ----
        {
            int colb = w * 32 + (lane & 15);
            int rq = (lane >> 4) * 4;
#pragma unroll
            for (int r = 0; r < 4; ++r) {
                E_s[rq + r][colb]      = acc0[r];
                E_s[rq + r][colb + 16] = acc1[r];
            }
        }
        __syncthreads();

        // ---- gates + h update ----
#pragma unroll
        for (int s = 0; s < 2; ++s) {
            int i = tid * 2 + s;
            int bl = i >> 5, jh = i & 31;
            int b = r0 + bl;
            int JH = bx * 32 + jh;
            float4 p  = *(const float4*)&E_s[bl][jh * 4];
            float4 bi = *(const float4*)&biasc[JH * 4];
            float rr = 1.f / (1.f + expf(-(p.x + bi.x)));
            float zz = 1.f / (1.f + expf(-(p.y + bi.y)));
            float nn = tanhf(p.z + bi.z + rr * (p.w + bi.w));
            float hp = (t == 0) ? 0.f
                                : hprev[b * Hh + JH] * b2f(gamma[((size_t)t * Bb + b) * Hh + JH]);
            float hn = (1.f - zz) * nn + zz * hp;
            hnext[b * Hh + JH] = hn;
            hs[(size_t)b * (Tt * Hh) + (size_t)t * Hh + JH] = hn;
            if (t == Tt - 1) hlast[(size_t)b * Hh + JH] = hn;
        }
        __syncthreads();   // all h stores issued; A_s/E_s safe to reuse

        // ---- row-group barrier (16 blocks sharing `by`) ----
        if (t < Tt - 1) {
            if (w == 0) {
                __threadfence();   // release: drain + write back L2 (cross-XCD visibility)
                if (lane == 0)
                    __hip_atomic_store(&bar[by * 16 + bx], (u32)(t + 1),
                                       __ATOMIC_RELAXED, __HIP_MEMORY_SCOPE_AGENT);
                bool done;
                do {
                    u32 v = (lane < 16)
                        ? __hip_atomic_load(&bar[by * 16 + lane],
                                            __ATOMIC_RELAXED, __HIP_MEMORY_SCOPE_AGENT)
                        : 0xFFFFFFFFu;
                    done = __all(v > (u32)t);
                    if (!done) __builtin_amdgcn_s_sleep(1);
                } while (!done);
                __threadfence();   // acquire: invalidate stale L1/L2 before h reads
            }
            __syncthreads();
        }
    }
}

extern "C" void kernel_launch(void* const* d_in, const int* in_sizes, int n_in,
                              void* d_out, int out_size, void* d_ws, size_t ws_size,
                              hipStream_t stream) {
    const float* values = (const float*)d_in[0];
    const float* masks  = (const float*)d_in[1];
    const float* deltas = (const float*)d_in[2];
    const float* emean  = (const float*)d_in[3];
    const float* locf   = (const float*)d_in[4];
    const float* wx     = (const float*)d_in[5];
    const float* bxp    = (const float*)d_in[6];
    const float* Wh     = (const float*)d_in[7];
    const float* bh     = (const float*)d_in[8];
    const float* W_ih   = (const float*)d_in[9];
    const float* W_hh   = (const float*)d_in[10];
    const float* b_ih   = (const float*)d_in[11];
    const float* b_hh   = (const float*)d_in[12];

    char* wsb    = (char*)d_ws;
    u16*  gamma  = (u16*)(wsb + OFF_GAMMA);
    u16*  xrep   = (u16*)(wsb + OFF_XREP);
    u16*  mbf    = (u16*)(wsb + OFF_MBF);
    u16*  wfrag  = (u16*)(wsb + OFF_WFRAG);
    u16*  whfrag = (u16*)(wsb + OFF_WHFRAG);
    float* biasc = (float*)(wsb + OFF_BIASC);
    float* hbuf  = (float*)(wsb + OFF_HBUF);
    u32*  bar    = (u32*)(wsb + OFF_BAR);
    float* hs    = (float*)d_out;
    float* hlast = hs + (size_t)Bb * Tt * Hh;

    k_prep<<<(Bb * Tt * Ff / 4) / 256, 256, 0, stream>>>(values, masks, deltas, locf,
                                                         emean, wx, bxp, xrep, mbf);
    k_wh<<<64, 256, 0, stream>>>(Wh, whfrag);
    k_gamma2<<<dim3((Tt * Bb) / 64, Hh / 64), 256, 0, stream>>>(deltas, whfrag, bh, gamma);
    k_wcomb<<<(NC * KTOT / 8) / 256, 256, 0, stream>>>(W_ih, W_hh, b_ih, b_hh, wfrag, biasc);
    k_zero_bar<<<1, 256, 0, stream>>>(bar);
    k_scan<<<256, 256, 0, stream>>>(xrep, mbf, gamma, wfrag, biasc, hbuf, bar, hs, hlast);
}